// Round 1
// baseline (3060.366 us; speedup 1.0000x reference)
//
#include <hip/hip_runtime.h>
#include <math.h>

#define CC 64
#define HW 4096
#define NB 4
#define NT 10
#define TH 16
#define LROW 68
#define LIC (18*LROW)
#define ICCH 8

__device__ __forceinline__ float sigm(float x) { return 1.0f / (1.0f + expf(-x)); }

// Kernel A: rz = conv3x3(prev_y, w_rz) + b_rz  (129 channels)
// epilogue: u = sigmoid(z + xi_z); ry = prev_y * sigmoid(r + xi_r); thr = sigmoid(thr_logit)
__global__ __launch_bounds__(256) void convA_kernel(
    const float* __restrict__ prev_y,
    const float* __restrict__ xt_t,
    const float* __restrict__ w_rz,
    const float* __restrict__ b_rz,
    float* __restrict__ ws_u,
    float* __restrict__ ws_ry,
    float* __restrict__ ws_thr,
    int first)
{
    __shared__ float lds[ICCH * LIC];
    const int tx = threadIdx.x & 15;   // col group: cols 4*tx .. 4*tx+3
    const int ty = threadIdx.x >> 4;   // row in tile
    const int ocg = blockIdx.x;        // 0..16 (group 16 -> channel 128 only)
    const int r0  = blockIdx.y * TH;
    const int b   = blockIdx.z;
    const int oc_base = ocg * 8;

    float acc[8][4];
#pragma unroll
    for (int o = 0; o < 8; ++o)
#pragma unroll
        for (int p = 0; p < 4; ++p) acc[o][p] = 0.f;

    if (!first) {
        for (int cg = 0; cg < CC / ICCH; ++cg) {
            __syncthreads();
            const float* src = prev_y + ((size_t)b * CC + cg * ICCH) * HW;
            for (int idx = threadIdx.x; idx < ICCH * LIC; idx += 256) {
                int ic  = idx / LIC;
                int rem = idx - ic * LIC;
                int row = rem / LROW;
                int col = rem - row * LROW;
                int sr = r0 - 1 + row;
                int sc = col - 1;
                float v = 0.f;
                if (sr >= 0 && sr < 64 && sc >= 0 && sc < 64)
                    v = src[ic * HW + sr * 64 + sc];
                lds[idx] = v;
            }
            __syncthreads();
            for (int ic = 0; ic < ICCH; ++ic) {
                float win[3][8];
#pragma unroll
                for (int dr = 0; dr < 3; ++dr) {
                    const float4* lp = (const float4*)&lds[ic * LIC + (ty + dr) * LROW + 4 * tx];
                    float4 a = lp[0], c = lp[1];
                    win[dr][0]=a.x; win[dr][1]=a.y; win[dr][2]=a.z; win[dr][3]=a.w;
                    win[dr][4]=c.x; win[dr][5]=c.y; win[dr][6]=c.z; win[dr][7]=c.w;
                }
                const int icg = cg * ICCH + ic;
#pragma unroll
                for (int o = 0; o < 8; ++o) {
                    int ocw = oc_base + o;
                    if (ocw > 128) ocw = 128;        // avoid OOB weight read for pad channels
                    const float* w9 = w_rz + ((size_t)ocw * CC + icg) * 9;
                    float w0=w9[0],w1=w9[1],w2=w9[2],w3=w9[3],w4=w9[4];
                    float w5=w9[5],w6=w9[6],w7=w9[7],w8=w9[8];
#pragma unroll
                    for (int p = 0; p < 4; ++p) {
                        float s = acc[o][p];
                        s = fmaf(w0, win[0][p],   s);
                        s = fmaf(w1, win[0][p+1], s);
                        s = fmaf(w2, win[0][p+2], s);
                        s = fmaf(w3, win[1][p],   s);
                        s = fmaf(w4, win[1][p+1], s);
                        s = fmaf(w5, win[1][p+2], s);
                        s = fmaf(w6, win[2][p],   s);
                        s = fmaf(w7, win[2][p+1], s);
                        s = fmaf(w8, win[2][p+2], s);
                        acc[o][p] = s;
                    }
                }
            }
        }
    }

    const int gr = r0 + ty;
    const int gc = tx * 4;
    const size_t pix = (size_t)gr * 64 + gc;
#pragma unroll
    for (int o = 0; o < 8; ++o) {
        int oc = oc_base + o;
        if (oc < CC) {
            float bias = b_rz[oc];
            const float4 x4 = *(const float4*)(xt_t + ((size_t)b * 192 + oc) * HW + pix);
            float4 outv;
            outv.x = sigm(acc[o][0] + bias + x4.x);
            outv.y = sigm(acc[o][1] + bias + x4.y);
            outv.z = sigm(acc[o][2] + bias + x4.z);
            outv.w = sigm(acc[o][3] + bias + x4.w);
            *(float4*)(ws_u + ((size_t)b * CC + oc) * HW + pix) = outv;
        } else if (oc < 2 * CC) {
            int c = oc - CC;
            float bias = b_rz[oc];
            const float4 x4 = *(const float4*)(xt_t + ((size_t)b * 192 + CC + c) * HW + pix);
            float4 py;
            if (first) { py = make_float4(0.f, 0.f, 0.f, 0.f); }
            else       { py = *(const float4*)(prev_y + ((size_t)b * CC + c) * HW + pix); }
            float4 outv;
            outv.x = py.x * sigm(acc[o][0] + bias + x4.x);
            outv.y = py.y * sigm(acc[o][1] + bias + x4.y);
            outv.z = py.z * sigm(acc[o][2] + bias + x4.z);
            outv.w = py.w * sigm(acc[o][3] + bias + x4.w);
            *(float4*)(ws_ry + ((size_t)b * CC + c) * HW + pix) = outv;
        } else if (oc == 2 * CC) {
            float bias = b_rz[2 * CC];
            float4 outv;
            outv.x = sigm(acc[o][0] + bias);
            outv.y = sigm(acc[o][1] + bias);
            outv.z = sigm(acc[o][2] + bias);
            outv.w = sigm(acc[o][3] + bias);
            *(float4*)(ws_thr + (size_t)b * HW + pix) = outv;
        }
    }
}

// Kernel B: f = conv3x3(ry, w_f) + b_f + xi_f; GRU update + spike epilogue
__global__ __launch_bounds__(256) void convB_kernel(
    const float* __restrict__ ry,
    const float* __restrict__ xt_t,
    const float* __restrict__ w_f,
    const float* __restrict__ b_f,
    const float* __restrict__ ws_u,
    const float* __restrict__ ws_thr,
    float* __restrict__ ws_h,
    float* __restrict__ out_y,
    float* __restrict__ out_e,
    float* __restrict__ out_nd,
    int first)
{
    __shared__ float lds[ICCH * LIC];
    const int tx = threadIdx.x & 15;
    const int ty = threadIdx.x >> 4;
    const int ocg = blockIdx.x;        // 0..15
    const int r0  = blockIdx.y * TH;
    const int b   = blockIdx.z;
    const int oc_base = ocg * 4;

    float acc[4][4];
#pragma unroll
    for (int o = 0; o < 4; ++o)
#pragma unroll
        for (int p = 0; p < 4; ++p) acc[o][p] = 0.f;

    for (int cg = 0; cg < CC / ICCH; ++cg) {
        __syncthreads();
        const float* src = ry + ((size_t)b * CC + cg * ICCH) * HW;
        for (int idx = threadIdx.x; idx < ICCH * LIC; idx += 256) {
            int ic  = idx / LIC;
            int rem = idx - ic * LIC;
            int row = rem / LROW;
            int col = rem - row * LROW;
            int sr = r0 - 1 + row;
            int sc = col - 1;
            float v = 0.f;
            if (sr >= 0 && sr < 64 && sc >= 0 && sc < 64)
                v = src[ic * HW + sr * 64 + sc];
            lds[idx] = v;
        }
        __syncthreads();
        for (int ic = 0; ic < ICCH; ++ic) {
            float win[3][8];
#pragma unroll
            for (int dr = 0; dr < 3; ++dr) {
                const float4* lp = (const float4*)&lds[ic * LIC + (ty + dr) * LROW + 4 * tx];
                float4 a = lp[0], c = lp[1];
                win[dr][0]=a.x; win[dr][1]=a.y; win[dr][2]=a.z; win[dr][3]=a.w;
                win[dr][4]=c.x; win[dr][5]=c.y; win[dr][6]=c.z; win[dr][7]=c.w;
            }
            const int icg = cg * ICCH + ic;
#pragma unroll
            for (int o = 0; o < 4; ++o) {
                int oc = oc_base + o;
                const float* w9 = w_f + ((size_t)oc * CC + icg) * 9;
                float w0=w9[0],w1=w9[1],w2=w9[2],w3=w9[3],w4=w9[4];
                float w5=w9[5],w6=w9[6],w7=w9[7],w8=w9[8];
#pragma unroll
                for (int p = 0; p < 4; ++p) {
                    float s = acc[o][p];
                    s = fmaf(w0, win[0][p],   s);
                    s = fmaf(w1, win[0][p+1], s);
                    s = fmaf(w2, win[0][p+2], s);
                    s = fmaf(w3, win[1][p],   s);
                    s = fmaf(w4, win[1][p+1], s);
                    s = fmaf(w5, win[1][p+2], s);
                    s = fmaf(w6, win[2][p],   s);
                    s = fmaf(w7, win[2][p+1], s);
                    s = fmaf(w8, win[2][p+2], s);
                    acc[o][p] = s;
                }
            }
        }
    }

    const int gr = r0 + ty;
    const int gc = tx * 4;
    const size_t pix = (size_t)gr * 64 + gc;
    const float4 t4 = *(const float4*)(ws_thr + (size_t)b * HW + pix);
#pragma unroll
    for (int o = 0; o < 4; ++o) {
        int oc = oc_base + o;
        float bias = b_f[oc];
        const size_t coff = ((size_t)b * CC + oc) * HW + pix;
        const float4 x4 = *(const float4*)(xt_t + ((size_t)b * 192 + 2 * CC + oc) * HW + pix);
        const float4 u4 = *(const float4*)(ws_u + coff);
        float4 h4;
        if (first) { h4 = make_float4(0.f, 0.f, 0.f, 0.f); }
        else       { h4 = *(const float4*)(ws_h + coff); }

        float fx[4] = { acc[o][0] + bias + x4.x, acc[o][1] + bias + x4.y,
                        acc[o][2] + bias + x4.z, acc[o][3] + bias + x4.w };
        float uu[4] = { u4.x, u4.y, u4.z, u4.w };
        float hh[4] = { h4.x, h4.y, h4.z, h4.w };
        float tt[4] = { t4.x, t4.y, t4.z, t4.w };
        float yv[4], ev[4], nd[4], hc[4];
#pragma unroll
        for (int j = 0; j < 4; ++j) {
            float ig = tanhf(fx[j]);
            float hn = (1.f - uu[j]) * hh[j] + uu[j] * ig;
            float d  = hn - tt[j];
            bool pos = d > 0.f;
            ev[j] = pos ? 1.f : 0.f;
            yv[j] = pos ? hn : 0.f;
            nd[j] = (d < 0.f) ? (tt[j] - hn) : 0.f;
            hc[j] = pos ? (hn - tt[j]) : hn;
        }
        *(float4*)(out_y + coff)  = make_float4(yv[0], yv[1], yv[2], yv[3]);
        *(float4*)(out_e + coff)  = make_float4(ev[0], ev[1], ev[2], ev[3]);
        *(float4*)(out_nd + coff) = make_float4(nd[0], nd[1], nd[2], nd[3]);
        *(float4*)(ws_h + coff)   = make_float4(hc[0], hc[1], hc[2], hc[3]);
    }
}

extern "C" void kernel_launch(void* const* d_in, const int* in_sizes, int n_in,
                              void* d_out, int out_size, void* d_ws, size_t ws_size,
                              hipStream_t stream) {
    const float* xt   = (const float*)d_in[0];
    const float* w_rz = (const float*)d_in[1];
    const float* b_rz = (const float*)d_in[2];
    const float* w_f  = (const float*)d_in[3];
    const float* b_f  = (const float*)d_in[4];
    float* out = (float*)d_out;
    float* ws  = (float*)d_ws;

    const size_t NCHW = (size_t)NB * CC * HW;   // 1,048,576 floats
    float* ws_u   = ws;
    float* ws_ry  = ws + NCHW;
    float* ws_thr = ws + 2 * NCHW;
    float* ws_h   = ws + 2 * NCHW + (size_t)NB * HW;

    float* ys  = out;
    float* es  = out + (size_t)NT * NCHW;
    float* nds = out + 2 * (size_t)NT * NCHW;

    for (int t = 0; t < NT; ++t) {
        const float* xtt = xt + (size_t)t * NB * 192 * HW;
        const float* py  = (t == 0) ? xtt : (ys + (size_t)(t - 1) * NCHW);
        hipLaunchKernelGGL(convA_kernel, dim3(17, 4, 4), dim3(256), 0, stream,
                           py, xtt, w_rz, b_rz, ws_u, ws_ry, ws_thr, (t == 0) ? 1 : 0);
        hipLaunchKernelGGL(convB_kernel, dim3(16, 4, 4), dim3(256), 0, stream,
                           ws_ry, xtt, w_f, b_f, ws_u, ws_thr, ws_h,
                           ys + (size_t)t * NCHW, es + (size_t)t * NCHW,
                           nds + (size_t)t * NCHW, (t == 0) ? 1 : 0);
    }
}

// Round 2
// 1303.547 us; speedup vs baseline: 2.3477x; 2.3477x over previous
//
#include <hip/hip_runtime.h>
#include <math.h>

#define CC 64
#define HW 4096
#define NB 4
#define NT 10
#define TR 4                 // tile rows per block
#define LROW 68              // 64 cols + 2 halo + 2 pad
#define LICS 412             // per-ic LDS stride (6*68=408, padded to %4==0 for float4)
#define ICCH 16              // input channels staged per chunk
#define CHUNK_LOGICAL (ICCH*408)

__device__ __forceinline__ float sigm(float x) { return 1.0f / (1.0f + expf(-x)); }

// ---------------------------------------------------------------------------
// Kernel A: rz = conv3x3(prev_y, w_rz) + b_rz (129 ch)
// thread layout: tx(16 cols x4) * ty(4 rows) * ocq(4), 4 oc per thread.
// ocg 0..3 -> z channels 0..63 ; ocg 4..7 -> r channels 64..127 ; ocg 8 -> thr (128)
// ---------------------------------------------------------------------------
__global__ __launch_bounds__(256) void convA_kernel(
    const float* __restrict__ prev_y,
    const float* __restrict__ xt_t,
    const float* __restrict__ w_rz,
    const float* __restrict__ b_rz,
    float* __restrict__ ws_u,
    float* __restrict__ ws_ry,
    float* __restrict__ ws_thr,
    int first)
{
    __shared__ float lds[ICCH * LICS];
    const int tx  = threadIdx.x & 15;
    const int t4  = (threadIdx.x >> 4) & 3;
    const int ocq = threadIdx.x >> 6;          // wave index == oc quad (wave-uniform)
    const int ocg = blockIdx.x;                // 0..8
    const int r0  = blockIdx.y * TR;
    const int b   = blockIdx.z;

    float acc[4][4];
#pragma unroll
    for (int o = 0; o < 4; ++o)
#pragma unroll
        for (int p = 0; p < 4; ++p) acc[o][p] = 0.f;

    if (!first) {
        const int oc_qs = __builtin_amdgcn_readfirstlane(ocq);  // scalar -> s_load weights
        for (int cg = 0; cg < CC / ICCH; ++cg) {
            __syncthreads();
            const float* src = prev_y + ((size_t)b * CC + cg * ICCH) * HW;
            for (int idx = threadIdx.x; idx < CHUNK_LOGICAL; idx += 256) {
                int ic  = idx / 408;
                int rem = idx - ic * 408;
                int row = rem / 68;
                int col = rem - row * 68;
                int sr = r0 - 1 + row;
                int sc = col - 1;
                float v = 0.f;
                if (sr >= 0 && sr < 64 && sc >= 0 && sc < 64)
                    v = src[ic * HW + sr * 64 + sc];
                lds[ic * LICS + rem] = v;
            }
            __syncthreads();
            for (int ic = 0; ic < ICCH; ++ic) {
                float win[3][8];
#pragma unroll
                for (int dr = 0; dr < 3; ++dr) {
                    const float4* lp = (const float4*)&lds[ic * LICS + (t4 + dr) * 68 + 4 * tx];
                    float4 a = lp[0], c = lp[1];
                    win[dr][0]=a.x; win[dr][1]=a.y; win[dr][2]=a.z; win[dr][3]=a.w;
                    win[dr][4]=c.x; win[dr][5]=c.y; win[dr][6]=c.z; win[dr][7]=c.w;
                }
                const int icg = cg * ICCH + ic;
#pragma unroll
                for (int o = 0; o < 4; ++o) {
                    int ocw = ocg * 16 + oc_qs * 4 + o;
                    if (ocw > 128) ocw = 128;           // pad lanes read valid mem, result unused
                    const float* w9 = w_rz + ((size_t)ocw * CC + icg) * 9;
                    float w0=w9[0],w1=w9[1],w2=w9[2],w3=w9[3],w4=w9[4];
                    float w5=w9[5],w6=w9[6],w7=w9[7],w8=w9[8];
#pragma unroll
                    for (int p = 0; p < 4; ++p) {
                        float s = acc[o][p];
                        s = fmaf(w0, win[0][p],   s);
                        s = fmaf(w1, win[0][p+1], s);
                        s = fmaf(w2, win[0][p+2], s);
                        s = fmaf(w3, win[1][p],   s);
                        s = fmaf(w4, win[1][p+1], s);
                        s = fmaf(w5, win[1][p+2], s);
                        s = fmaf(w6, win[2][p],   s);
                        s = fmaf(w7, win[2][p+1], s);
                        s = fmaf(w8, win[2][p+2], s);
                        acc[o][p] = s;
                    }
                }
            }
        }
    }

    const int gr = r0 + t4;
    const size_t pix = (size_t)gr * 64 + 4 * tx;

    if (ocg < 4) {                       // z-type: update gate
#pragma unroll
        for (int o = 0; o < 4; ++o) {
            int oc = ocg * 16 + ocq * 4 + o;
            float bias = b_rz[oc];
            const float4 x4 = *(const float4*)(xt_t + ((size_t)b * 192 + oc) * HW + pix);
            float4 outv;
            outv.x = sigm(acc[o][0] + bias + x4.x);
            outv.y = sigm(acc[o][1] + bias + x4.y);
            outv.z = sigm(acc[o][2] + bias + x4.z);
            outv.w = sigm(acc[o][3] + bias + x4.w);
            *(float4*)(ws_u + ((size_t)b * CC + oc) * HW + pix) = outv;
        }
    } else if (ocg < 8) {                // r-type: ry = prev_y * reset_gate
#pragma unroll
        for (int o = 0; o < 4; ++o) {
            int oc = ocg * 16 + ocq * 4 + o;
            int c  = oc - CC;
            float bias = b_rz[oc];
            const float4 x4 = *(const float4*)(xt_t + ((size_t)b * 192 + oc) * HW + pix);
            float4 py;
            if (first) { py = make_float4(0.f, 0.f, 0.f, 0.f); }
            else       { py = *(const float4*)(prev_y + ((size_t)b * CC + c) * HW + pix); }
            float4 outv;
            outv.x = py.x * sigm(acc[o][0] + bias + x4.x);
            outv.y = py.y * sigm(acc[o][1] + bias + x4.y);
            outv.z = py.z * sigm(acc[o][2] + bias + x4.z);
            outv.w = py.w * sigm(acc[o][3] + bias + x4.w);
            *(float4*)(ws_ry + ((size_t)b * CC + c) * HW + pix) = outv;
        }
    } else {                             // thr channel (oc 128): only ocq==0, o==0 is real
        if (ocq == 0) {
            float bias = b_rz[2 * CC];
            float4 outv;
            outv.x = sigm(acc[0][0] + bias);
            outv.y = sigm(acc[0][1] + bias);
            outv.z = sigm(acc[0][2] + bias);
            outv.w = sigm(acc[0][3] + bias);
            *(float4*)(ws_thr + (size_t)b * HW + pix) = outv;
        }
    }
}

// ---------------------------------------------------------------------------
// Kernel B-conv: partial f = conv3x3(ry, w_f) over an ic half (split-K 2-way).
// Partials land in the es[t] / nds[t] output slabs (overwritten by the epilogue).
// ---------------------------------------------------------------------------
__global__ __launch_bounds__(256) void convB_kernel(
    const float* __restrict__ ry,
    const float* __restrict__ w_f,
    float* __restrict__ part0,
    float* __restrict__ part1)
{
    __shared__ float lds[ICCH * LICS];
    const int tx  = threadIdx.x & 15;
    const int t4  = (threadIdx.x >> 4) & 3;
    const int ocq = threadIdx.x >> 6;
    const int ocg = blockIdx.x & 3;            // 0..3
    const int ks  = blockIdx.x >> 2;           // 0..1 ic half
    const int r0  = blockIdx.y * TR;
    const int b   = blockIdx.z;

    float acc[4][4];
#pragma unroll
    for (int o = 0; o < 4; ++o)
#pragma unroll
        for (int p = 0; p < 4; ++p) acc[o][p] = 0.f;

    const int oc_qs = __builtin_amdgcn_readfirstlane(ocq);
    for (int cg = 0; cg < 2; ++cg) {           // 2 chunks of 16 ic = this half
        __syncthreads();
        const int icbase = ks * 32 + cg * ICCH;
        const float* src = ry + ((size_t)b * CC + icbase) * HW;
        for (int idx = threadIdx.x; idx < CHUNK_LOGICAL; idx += 256) {
            int ic  = idx / 408;
            int rem = idx - ic * 408;
            int row = rem / 68;
            int col = rem - row * 68;
            int sr = r0 - 1 + row;
            int sc = col - 1;
            float v = 0.f;
            if (sr >= 0 && sr < 64 && sc >= 0 && sc < 64)
                v = src[ic * HW + sr * 64 + sc];
            lds[ic * LICS + rem] = v;
        }
        __syncthreads();
        for (int ic = 0; ic < ICCH; ++ic) {
            float win[3][8];
#pragma unroll
            for (int dr = 0; dr < 3; ++dr) {
                const float4* lp = (const float4*)&lds[ic * LICS + (t4 + dr) * 68 + 4 * tx];
                float4 a = lp[0], c = lp[1];
                win[dr][0]=a.x; win[dr][1]=a.y; win[dr][2]=a.z; win[dr][3]=a.w;
                win[dr][4]=c.x; win[dr][5]=c.y; win[dr][6]=c.z; win[dr][7]=c.w;
            }
            const int icg = icbase + ic;
#pragma unroll
            for (int o = 0; o < 4; ++o) {
                int oc = ocg * 16 + oc_qs * 4 + o;
                const float* w9 = w_f + ((size_t)oc * CC + icg) * 9;
                float w0=w9[0],w1=w9[1],w2=w9[2],w3=w9[3],w4=w9[4];
                float w5=w9[5],w6=w9[6],w7=w9[7],w8=w9[8];
#pragma unroll
                for (int p = 0; p < 4; ++p) {
                    float s = acc[o][p];
                    s = fmaf(w0, win[0][p],   s);
                    s = fmaf(w1, win[0][p+1], s);
                    s = fmaf(w2, win[0][p+2], s);
                    s = fmaf(w3, win[1][p],   s);
                    s = fmaf(w4, win[1][p+1], s);
                    s = fmaf(w5, win[1][p+2], s);
                    s = fmaf(w6, win[2][p],   s);
                    s = fmaf(w7, win[2][p+1], s);
                    s = fmaf(w8, win[2][p+2], s);
                    acc[o][p] = s;
                }
            }
        }
    }

    const int gr = r0 + t4;
    const size_t pix = (size_t)gr * 64 + 4 * tx;
    float* part = ks ? part1 : part0;
#pragma unroll
    for (int o = 0; o < 4; ++o) {
        int oc = ocg * 16 + ocq * 4 + o;
        *(float4*)(part + ((size_t)b * CC + oc) * HW + pix) =
            make_float4(acc[o][0], acc[o][1], acc[o][2], acc[o][3]);
    }
}

// ---------------------------------------------------------------------------
// Kernel B-epi: f = part0+part1+b_f+xi_f ; GRU update + spike epilogue.
// Reads partials from es[t]/nds[t], overwrites them with final e / neg_dist.
// ---------------------------------------------------------------------------
__global__ __launch_bounds__(256) void convB_epi(
    const float* __restrict__ xt_t,
    const float* __restrict__ b_f,
    const float* __restrict__ ws_u,
    const float* __restrict__ ws_thr,
    float* __restrict__ ws_h,
    float* __restrict__ out_y,
    float* __restrict__ out_e,
    float* __restrict__ out_nd,
    int first)
{
    const int i = blockIdx.x * 256 + threadIdx.x;   // one float4 per thread
    const int b   = i >> 16;                        // 65536 quads per batch
    const int rem = i & 65535;
    const int c   = rem >> 10;
    const int p4  = rem & 1023;
    const size_t off = ((size_t)(b * CC + c)) * HW + 4 * p4;
    const size_t pix = (size_t)4 * p4;

    const float4 f0 = *(const float4*)(out_e + off);
    const float4 f1 = *(const float4*)(out_nd + off);
    const float4 x4 = *(const float4*)(xt_t + ((size_t)b * 192 + 2 * CC + c) * HW + 4 * p4);
    const float4 u4 = *(const float4*)(ws_u + off);
    const float4 t4 = *(const float4*)(ws_thr + (size_t)b * HW + pix);
    float bias = b_f[c];
    float4 h4;
    if (first) { h4 = make_float4(0.f, 0.f, 0.f, 0.f); }
    else       { h4 = *(const float4*)(ws_h + off); }

    float fx[4] = { f0.x + f1.x + bias + x4.x, f0.y + f1.y + bias + x4.y,
                    f0.z + f1.z + bias + x4.z, f0.w + f1.w + bias + x4.w };
    float uu[4] = { u4.x, u4.y, u4.z, u4.w };
    float hh[4] = { h4.x, h4.y, h4.z, h4.w };
    float tt[4] = { t4.x, t4.y, t4.z, t4.w };
    float yv[4], ev[4], nd[4], hc[4];
#pragma unroll
    for (int j = 0; j < 4; ++j) {
        float ig = tanhf(fx[j]);
        float hn = (1.f - uu[j]) * hh[j] + uu[j] * ig;
        float d  = hn - tt[j];
        bool pos = d > 0.f;
        ev[j] = pos ? 1.f : 0.f;
        yv[j] = pos ? hn : 0.f;
        nd[j] = (d < 0.f) ? (tt[j] - hn) : 0.f;
        hc[j] = pos ? (hn - tt[j]) : hn;
    }
    *(float4*)(out_y + off)  = make_float4(yv[0], yv[1], yv[2], yv[3]);
    *(float4*)(out_e + off)  = make_float4(ev[0], ev[1], ev[2], ev[3]);
    *(float4*)(out_nd + off) = make_float4(nd[0], nd[1], nd[2], nd[3]);
    *(float4*)(ws_h + off)   = make_float4(hc[0], hc[1], hc[2], hc[3]);
}

extern "C" void kernel_launch(void* const* d_in, const int* in_sizes, int n_in,
                              void* d_out, int out_size, void* d_ws, size_t ws_size,
                              hipStream_t stream) {
    const float* xt   = (const float*)d_in[0];
    const float* w_rz = (const float*)d_in[1];
    const float* b_rz = (const float*)d_in[2];
    const float* w_f  = (const float*)d_in[3];
    const float* b_f  = (const float*)d_in[4];
    float* out = (float*)d_out;
    float* ws  = (float*)d_ws;

    const size_t NCHW = (size_t)NB * CC * HW;   // 1,048,576 floats
    float* ws_u   = ws;
    float* ws_ry  = ws + NCHW;
    float* ws_thr = ws + 2 * NCHW;
    float* ws_h   = ws + 2 * NCHW + (size_t)NB * HW;

    float* ys  = out;
    float* es  = out + (size_t)NT * NCHW;
    float* nds = out + 2 * (size_t)NT * NCHW;

    for (int t = 0; t < NT; ++t) {
        const float* xtt = xt + (size_t)t * NB * 192 * HW;
        const float* py  = (t == 0) ? xtt : (ys + (size_t)(t - 1) * NCHW);
        hipLaunchKernelGGL(convA_kernel, dim3(9, 16, 4), dim3(256), 0, stream,
                           py, xtt, w_rz, b_rz, ws_u, ws_ry, ws_thr, (t == 0) ? 1 : 0);
        hipLaunchKernelGGL(convB_kernel, dim3(8, 16, 4), dim3(256), 0, stream,
                           ws_ry, w_f, es + (size_t)t * NCHW, nds + (size_t)t * NCHW);
        hipLaunchKernelGGL(convB_epi, dim3(1024), dim3(256), 0, stream,
                           xtt, b_f, ws_u, ws_thr, ws_h,
                           ys + (size_t)t * NCHW, es + (size_t)t * NCHW,
                           nds + (size_t)t * NCHW, (t == 0) ? 1 : 0);
    }
}